// Round 11
// baseline (332.747 us; speedup 1.0000x reference)
//
#include <hip/hip_runtime.h>
#include <math.h>

// Problem constants
#define B_   8
#define L_   256
#define C_   512
#define OUT_ 512

typedef _Float16 half8 __attribute__((ext_vector_type(8)));
typedef float    f32x4 __attribute__((ext_vector_type(4)));
typedef float    f32x2 __attribute__((ext_vector_type(2)));

// ---------------------------------------------------------------------------
// Kernel 1: MFMA relu-GEMM projections (f32 in, f16 frags, f32 acc, f16 out).
//   Y[m][n] = sum_k relu(X[m][k]) * W[k][n] + bias[n],  W raw f32 [k][n].
// 64x64 tile, KT=32, dbuf, 1 barrier/step, grid (8,32,2).
// Also zeroes P and the completion counters (replaces memset dispatches).
// ---------------------------------------------------------------------------
__global__ __launch_bounds__(256)
void proj_mfma_kernel(const float* __restrict__ xt, const float* __restrict__ Wp,
                      const float* __restrict__ bp,
                      const float* __restrict__ xd, const float* __restrict__ Wc,
                      const float* __restrict__ bc,
                      _Float16* __restrict__ pt, _Float16* __restrict__ pc,
                      float* __restrict__ P, int* __restrict__ cnt)
{
    const int which = blockIdx.z;
    const float* __restrict__ X    = which ? xd : xt;
    const float* __restrict__ W    = which ? Wc : Wp;
    const float* __restrict__ bias = which ? bc : bp;
    _Float16*    __restrict__ Y    = which ? pc : pt;

    // fold P/cnt zeroing into this kernel (stream order precedes cp)
    if (which == 0 && blockIdx.y == 0) {
        const int pb = (int)blockIdx.x << 9;
        P[pb | threadIdx.x]         = 0.f;
        P[pb | (threadIdx.x + 256)] = 0.f;
        if (threadIdx.x == 0) cnt[blockIdx.x] = 0;
    }

    __shared__ _Float16 Ah[2][64][40];   // [buf][m][k]
    __shared__ _Float16 Bh[2][64][40];   // [buf][n][k]
    __shared__ _Float16 Ot[64][72];

    const int tid = threadIdx.x;
    const int m0 = blockIdx.y << 6, n0 = blockIdx.x << 6;
    const int lane = tid & 63, wv = tid >> 6;
    const int l15 = lane & 15, quad = lane >> 4;

    const int srow = tid >> 2, sch = (tid & 3) << 3;
    const float* Ag = X + (size_t)(m0 + srow) * C_ + sch;
    const int nl = tid & 63, kseg = tid >> 6;
    const float* Bg = W + (size_t)(kseg << 3) * C_ + n0 + nl;

    float4 a0 = *(const float4*)(Ag);
    float4 a1 = *(const float4*)(Ag + 4);
    float wr[8];
    #pragma unroll
    for (int r = 0; r < 8; ++r) wr[r] = Bg[(size_t)r * C_];

    {
        half8 av;
        av[0] = (_Float16)fmaxf(a0.x, 0.f); av[1] = (_Float16)fmaxf(a0.y, 0.f);
        av[2] = (_Float16)fmaxf(a0.z, 0.f); av[3] = (_Float16)fmaxf(a0.w, 0.f);
        av[4] = (_Float16)fmaxf(a1.x, 0.f); av[5] = (_Float16)fmaxf(a1.y, 0.f);
        av[6] = (_Float16)fmaxf(a1.z, 0.f); av[7] = (_Float16)fmaxf(a1.w, 0.f);
        *(half8*)&Ah[0][srow][sch] = av;
        half8 bv;
        #pragma unroll
        for (int r = 0; r < 8; ++r) bv[r] = (_Float16)wr[r];
        *(half8*)&Bh[0][nl][kseg << 3] = bv;
    }

    f32x4 acc[4] = {};
    for (int ks = 0; ks < 16; ++ks) {
        const int cur = ks & 1;
        if (ks < 15) {
            Ag += 32;
            Bg += 32 * C_;
            a0 = *(const float4*)(Ag);
            a1 = *(const float4*)(Ag + 4);
            #pragma unroll
            for (int r = 0; r < 8; ++r) wr[r] = Bg[(size_t)r * C_];
        }
        __syncthreads();
        half8 af = *(const half8*)&Ah[cur][(wv << 4) + l15][quad << 3];
        #pragma unroll
        for (int nb = 0; nb < 4; ++nb) {
            half8 bf = *(const half8*)&Bh[cur][(nb << 4) + l15][quad << 3];
            acc[nb] = __builtin_amdgcn_mfma_f32_16x16x32_f16(af, bf, acc[nb], 0, 0, 0);
        }
        if (ks < 15) {
            half8 av;
            av[0] = (_Float16)fmaxf(a0.x, 0.f); av[1] = (_Float16)fmaxf(a0.y, 0.f);
            av[2] = (_Float16)fmaxf(a0.z, 0.f); av[3] = (_Float16)fmaxf(a0.w, 0.f);
            av[4] = (_Float16)fmaxf(a1.x, 0.f); av[5] = (_Float16)fmaxf(a1.y, 0.f);
            av[6] = (_Float16)fmaxf(a1.z, 0.f); av[7] = (_Float16)fmaxf(a1.w, 0.f);
            *(half8*)&Ah[cur ^ 1][srow][sch] = av;
            half8 bv;
            #pragma unroll
            for (int r = 0; r < 8; ++r) bv[r] = (_Float16)wr[r];
            *(half8*)&Bh[cur ^ 1][nl][kseg << 3] = bv;
        }
    }

    __syncthreads();
    #pragma unroll
    for (int nb = 0; nb < 4; ++nb) {
        const float bz = bias[n0 + (nb << 4) + l15];
        #pragma unroll
        for (int r = 0; r < 4; ++r)
            Ot[(wv << 4) + (quad << 2) + r][(nb << 4) + l15] = (_Float16)(acc[nb][r] + bz);
    }
    __syncthreads();
    const int erow = tid >> 3, ech = (tid & 7) << 3;
    #pragma unroll
    for (int h = 0; h < 64; h += 32)
        *(half8*)&Y[(size_t)(m0 + erow + h) * C_ + n0 + ech] = *(const half8*)&Ot[erow + h][ech];
}

// ---------------------------------------------------------------------------
// Kernel 2 (FUSED, now also finalizes): per (i-tile 32, j-tile 16, b):
//  phase 1: dot tile via MFMA (K=512, dbuf), sigmoid -> ws_ LDS; tile sum.
//  phase 2: thread = channel: sum_{i,j} w*r(xd*xt), r = 1/(1+exp2(2log2e*x)).
//           Pair form WITHOUT swap: (w0*q1 + w1*q0)*rcp(q0*q1) — scalar
//           accumulators, f32x2 only for lane-parallel mul/add (pk-friendly).
//  epilogue: atomicAdd into P[b][c]; per-batch completion counter; the
//           128th block of each b runs the finalize (S, cp, out = cp@Wf+bf).
// grid (8,16,8) = 1024 blocks x 512 thr.
// ---------------------------------------------------------------------------
__device__ __forceinline__ float sigmoid_fast(float z) {
    float e = __builtin_amdgcn_exp2f(-1.4426950408889634f * z);
    return __builtin_amdgcn_rcpf(e + 1.0f);
}

__global__ __launch_bounds__(512, 4)
void cp_scores_kernel(const _Float16* __restrict__ pt, const _Float16* __restrict__ pc,
                      const float* __restrict__ xd, const float* __restrict__ xt,
                      float* __restrict__ P, float* __restrict__ sums_part,
                      int* __restrict__ cnt,
                      const float* __restrict__ Wf, const float* __restrict__ bfv,
                      float* __restrict__ out)
{
    const int bx = blockIdx.x, by = blockIdx.y, b = blockIdx.z;
    const int i0 = bx << 5, j0 = by << 4;
    const int tid = threadIdx.x;
    const int lane = tid & 63, wv = tid >> 6;
    const int l15 = lane & 15, quad = lane >> 4;

    __shared__ _Float16 Ah[2][32][40];   // pt rows (i)
    __shared__ _Float16 Bh[2][16][40];   // pc rows (j)
    __shared__ float ws_[16][36];        // [j][i]
    __shared__ float wred[2];
    __shared__ float sred[128];
    __shared__ float cpsh[C_];
    __shared__ int   lastFlag;

    // ---- phase 1: 32x16 dot tile, MFMA, dbuf; staging threads 0..191 ----
    const int srow = tid >> 2;            // 0..47 for tid<192
    const int sch  = (tid & 3) << 3;      // 0,8,16,24
    const _Float16* Sg = ((srow < 32) ? pt + (size_t)(b * L_ + i0 + srow) * C_
                                      : pc + (size_t)(b * L_ + j0 + (srow - 32)) * C_) + sch;

    half8 v = {};
    if (tid < 192) {
        v = *(const half8*)Sg;
        if (srow < 32) *(half8*)&Ah[0][srow][sch] = v;
        else           *(half8*)&Bh[0][srow - 32][sch] = v;
    }

    f32x4 dacc = {};
    for (int ks = 0; ks < 16; ++ks) {
        const int cur = ks & 1;
        if (ks < 15 && tid < 192) { Sg += 32; v = *(const half8*)Sg; }
        __syncthreads();
        if (wv < 2) {   // waves 0-1 own the 2 16x16 quadrants (m-block = wv)
            half8 af = *(const half8*)&Ah[cur][(wv << 4) + l15][quad << 3];
            half8 bf = *(const half8*)&Bh[cur][l15][quad << 3];
            dacc = __builtin_amdgcn_mfma_f32_16x16x32_f16(af, bf, dacc, 0, 0, 0);
        }
        if (ks < 15 && tid < 192) {
            if (srow < 32) *(half8*)&Ah[cur ^ 1][srow][sch] = v;
            else           *(half8*)&Bh[cur ^ 1][srow - 32][sch] = v;
        }
    }

    float lsum = 0.f;
    if (wv < 2) {
        // C/D: col(l15) = j, row(quad*4+r) = i within 16-block (i base = wv*16)
        float4 sg;
        sg.x = sigmoid_fast(dacc[0]);
        sg.y = sigmoid_fast(dacc[1]);
        sg.z = sigmoid_fast(dacc[2]);
        sg.w = sigmoid_fast(dacc[3]);
        *(float4*)&ws_[l15][(wv << 4) + (quad << 2)] = sg;
        lsum = (sg.x + sg.y) + (sg.z + sg.w);
    }
    #pragma unroll
    for (int off = 32; off; off >>= 1) lsum += __shfl_xor(lsum, off);
    if (wv < 2 && lane == 0) wred[wv] = lsum;
    __syncthreads();                                    // ws_ + wred ready
    if (tid == 0)
        sums_part[(b << 7) | (bx << 4) | by] = wred[0] + wred[1];

    // ---- phase 2: thread = channel; pair form, no swap, scalar accs ----
    const int c = tid;
    const float* __restrict__ xdb = xd + (size_t)(b * L_ + i0) * C_ + c;
    const float* __restrict__ xtb = xt + (size_t)(b * L_ + j0) * C_ + c;

    float total = 0.f;
    #pragma unroll
    for (int ih = 0; ih < 2; ++ih) {
        f32x2 xds2[8];                      // 16 live VGPRs
        #pragma unroll
        for (int i = 0; i < 8; ++i) {
            xds2[i][0] = xdb[(size_t)((ih << 4) + 2 * i) * C_]     * 2.8853900817779268f;
            xds2[i][1] = xdb[(size_t)((ih << 4) + 2 * i + 1) * C_] * 2.8853900817779268f;
        }
        float A0 = 0.f, A1 = 0.f, A2 = 0.f, A3 = 0.f;
        #pragma unroll 2
        for (int jj = 0; jj < 16; ++jj) {
            const float xv = xtb[(size_t)jj * C_];
            const f32x2 xvv = {xv, xv};
            #pragma unroll
            for (int g = 0; g < 4; ++g) {
                const float4 w4 = *(const float4*)&ws_[jj][(ih << 4) + (g << 2)];
                f32x2 x0 = xds2[(g << 1)]     * xvv;    // v_pk_mul_f32
                f32x2 x1 = xds2[(g << 1) + 1] * xvv;
                f32x2 e0 = { __builtin_amdgcn_exp2f(x0[0]), __builtin_amdgcn_exp2f(x0[1]) };
                f32x2 e1 = { __builtin_amdgcn_exp2f(x1[0]), __builtin_amdgcn_exp2f(x1[1]) };
                f32x2 q0 = e0 + 1.0f;                   // v_pk_add_f32
                f32x2 q1 = e1 + 1.0f;
                const float rp0 = __builtin_amdgcn_rcpf(q0[0] * q0[1]);
                const float rp1 = __builtin_amdgcn_rcpf(q1[0] * q1[1]);
                float t0 = w4.x * q0[1];
                t0 = fmaf(w4.y, q0[0], t0);
                float t1 = w4.z * q1[1];
                t1 = fmaf(w4.w, q1[0], t1);
                if (g & 1) { A2 = fmaf(t0, rp0, A2); A3 = fmaf(t1, rp1, A3); }
                else       { A0 = fmaf(t0, rp0, A0); A1 = fmaf(t1, rp1, A1); }
            }
        }
        total += ((A0 + A1) + (A2 + A3));
    }
    atomicAdd(&P[(b << 9) | c], total);

    // ---- completion protocol: 128th block of batch b finalizes ----
    __threadfence();                       // release my P-add (agent scope)
    __syncthreads();                       // order whole block's adds before cnt
    if (tid == 0) {
        int old = __hip_atomic_fetch_add(&cnt[b], 1, __ATOMIC_ACQ_REL,
                                         __HIP_MEMORY_SCOPE_AGENT);
        lastFlag = (old == 127);
    }
    __syncthreads();
    if (!lastFlag) return;

    __threadfence();                       // acquire side
    float sv = 0.f;
    if (tid < 128)
        sv = __hip_atomic_load(&sums_part[(b << 7) | tid], __ATOMIC_RELAXED,
                               __HIP_MEMORY_SCOPE_AGENT);
    if (tid < 128) sred[tid] = sv;
    __syncthreads();
    for (int st = 64; st > 0; st >>= 1) {
        if (tid < st) sred[tid] += sred[tid + st];
        __syncthreads();
    }
    const float invS = 2.0f / sred[0];

    const float pv = __hip_atomic_load(&P[(b << 9) | tid], __ATOMIC_RELAXED,
                                       __HIP_MEMORY_SCOPE_AGENT);
    cpsh[tid] = 1.0f - pv * invS;
    __syncthreads();

    float oacc = bfv[tid];
    #pragma unroll 8
    for (int cc = 0; cc < C_; ++cc)
        oacc = fmaf(cpsh[cc], Wf[(size_t)cc * OUT_ + tid], oacc);
    out[(size_t)b * OUT_ + tid] = oacc;
}

// ---------------------------------------------------------------------------
extern "C" void kernel_launch(void* const* d_in, const int* in_sizes, int n_in,
                              void* d_out, int out_size, void* d_ws, size_t ws_size,
                              hipStream_t stream)
{
    const float* xd = (const float*)d_in[0];
    const float* xt = (const float*)d_in[1];
    const float* Wc = (const float*)d_in[2];
    const float* bc = (const float*)d_in[3];
    const float* Wp = (const float*)d_in[4];
    const float* bp = (const float*)d_in[5];
    const float* Wf = (const float*)d_in[6];
    const float* bf = (const float*)d_in[7];
    float* out = (float*)d_out;

    // workspace (~4 MB)
    _Float16* pt  = (_Float16*)d_ws;                 // 2 MB
    _Float16* pc  = pt + 1048576;                    // 2 MB
    float* P         = (float*)(pc + 1048576);       // 8*512 fl
    float* sums_part = P + B_ * C_;                  // 1024 fl
    int*   cnt       = (int*)(sums_part + 1024);     // 8 ints

    proj_mfma_kernel<<<dim3(8, 32, 2), 256, 0, stream>>>(xt, Wp, bp, xd, Wc, bc,
                                                         pt, pc, P, cnt);
    cp_scores_kernel<<<dim3(8, 16, 8), 512, 0, stream>>>(pt, pc, xd, xt, P, sums_part,
                                                         cnt, Wf, bf, out);
}

// Round 12
// 151.682 us; speedup vs baseline: 2.1937x; 2.1937x over previous
//
#include <hip/hip_runtime.h>
#include <math.h>

// Problem constants
#define B_   8
#define L_   256
#define C_   512
#define OUT_ 512

typedef _Float16 half8 __attribute__((ext_vector_type(8)));
typedef float    f32x4 __attribute__((ext_vector_type(4)));
typedef float    f32x2 __attribute__((ext_vector_type(2)));

// ---------------------------------------------------------------------------
// Kernel 1: MFMA relu-GEMM projections (f32 in, f16 frags, f32 acc, f16 out).
//   Y[m][n] = sum_k relu(X[m][k]) * W[k][n] + bias[n],  W raw f32 [k][n].
// 64x64 tile, KT=32, dbuf, 1 barrier/step, grid (8,32,2).
// Also zeroes the P accumulator (replaces a memset dispatch).
// ---------------------------------------------------------------------------
__global__ __launch_bounds__(256)
void proj_mfma_kernel(const float* __restrict__ xt, const float* __restrict__ Wp,
                      const float* __restrict__ bp,
                      const float* __restrict__ xd, const float* __restrict__ Wc,
                      const float* __restrict__ bc,
                      _Float16* __restrict__ pt, _Float16* __restrict__ pc,
                      float* __restrict__ P)
{
    const int which = blockIdx.z;
    const float* __restrict__ X    = which ? xd : xt;
    const float* __restrict__ W    = which ? Wc : Wp;
    const float* __restrict__ bias = which ? bc : bp;
    _Float16*    __restrict__ Y    = which ? pc : pt;

    if (which == 0 && blockIdx.y == 0) {
        const int pb = (int)blockIdx.x << 9;
        P[pb | threadIdx.x]         = 0.f;
        P[pb | (threadIdx.x + 256)] = 0.f;
    }

    __shared__ _Float16 Ah[2][64][40];   // [buf][m][k]
    __shared__ _Float16 Bh[2][64][40];   // [buf][n][k]
    __shared__ _Float16 Ot[64][72];

    const int tid = threadIdx.x;
    const int m0 = blockIdx.y << 6, n0 = blockIdx.x << 6;
    const int lane = tid & 63, wv = tid >> 6;
    const int l15 = lane & 15, quad = lane >> 4;

    const int srow = tid >> 2, sch = (tid & 3) << 3;
    const float* Ag = X + (size_t)(m0 + srow) * C_ + sch;
    const int nl = tid & 63, kseg = tid >> 6;
    const float* Bg = W + (size_t)(kseg << 3) * C_ + n0 + nl;

    float4 a0 = *(const float4*)(Ag);
    float4 a1 = *(const float4*)(Ag + 4);
    float wr[8];
    #pragma unroll
    for (int r = 0; r < 8; ++r) wr[r] = Bg[(size_t)r * C_];

    {
        half8 av;
        av[0] = (_Float16)fmaxf(a0.x, 0.f); av[1] = (_Float16)fmaxf(a0.y, 0.f);
        av[2] = (_Float16)fmaxf(a0.z, 0.f); av[3] = (_Float16)fmaxf(a0.w, 0.f);
        av[4] = (_Float16)fmaxf(a1.x, 0.f); av[5] = (_Float16)fmaxf(a1.y, 0.f);
        av[6] = (_Float16)fmaxf(a1.z, 0.f); av[7] = (_Float16)fmaxf(a1.w, 0.f);
        *(half8*)&Ah[0][srow][sch] = av;
        half8 bv;
        #pragma unroll
        for (int r = 0; r < 8; ++r) bv[r] = (_Float16)wr[r];
        *(half8*)&Bh[0][nl][kseg << 3] = bv;
    }

    f32x4 acc[4] = {};
    for (int ks = 0; ks < 16; ++ks) {
        const int cur = ks & 1;
        if (ks < 15) {
            Ag += 32;
            Bg += 32 * C_;
            a0 = *(const float4*)(Ag);
            a1 = *(const float4*)(Ag + 4);
            #pragma unroll
            for (int r = 0; r < 8; ++r) wr[r] = Bg[(size_t)r * C_];
        }
        __syncthreads();
        half8 af = *(const half8*)&Ah[cur][(wv << 4) + l15][quad << 3];
        #pragma unroll
        for (int nb = 0; nb < 4; ++nb) {
            half8 bf = *(const half8*)&Bh[cur][(nb << 4) + l15][quad << 3];
            acc[nb] = __builtin_amdgcn_mfma_f32_16x16x32_f16(af, bf, acc[nb], 0, 0, 0);
        }
        if (ks < 15) {
            half8 av;
            av[0] = (_Float16)fmaxf(a0.x, 0.f); av[1] = (_Float16)fmaxf(a0.y, 0.f);
            av[2] = (_Float16)fmaxf(a0.z, 0.f); av[3] = (_Float16)fmaxf(a0.w, 0.f);
            av[4] = (_Float16)fmaxf(a1.x, 0.f); av[5] = (_Float16)fmaxf(a1.y, 0.f);
            av[6] = (_Float16)fmaxf(a1.z, 0.f); av[7] = (_Float16)fmaxf(a1.w, 0.f);
            *(half8*)&Ah[cur ^ 1][srow][sch] = av;
            half8 bv;
            #pragma unroll
            for (int r = 0; r < 8; ++r) bv[r] = (_Float16)wr[r];
            *(half8*)&Bh[cur ^ 1][nl][kseg << 3] = bv;
        }
    }

    __syncthreads();
    #pragma unroll
    for (int nb = 0; nb < 4; ++nb) {
        const float bz = bias[n0 + (nb << 4) + l15];
        #pragma unroll
        for (int r = 0; r < 4; ++r)
            Ot[(wv << 4) + (quad << 2) + r][(nb << 4) + l15] = (_Float16)(acc[nb][r] + bz);
    }
    __syncthreads();
    const int erow = tid >> 3, ech = (tid & 7) << 3;
    #pragma unroll
    for (int h = 0; h < 64; h += 32)
        *(half8*)&Y[(size_t)(m0 + erow + h) * C_ + n0 + ech] = *(const half8*)&Ot[erow + h][ech];
}

// ---------------------------------------------------------------------------
// Kernel 2 (FUSED): per (i-tile 32, j-tile 16, b), full c per block:
//  phase 1: dot tile via MFMA (K=512, dbuf), sigmoid -> ws_ LDS; tile sum.
//  phase 2: thread = channel: sum_{i,j} w*r(xd*xt), r = 1/(1+exp2(2log2e*x)).
//           Dot form (no swap): (w0*q1 + w1*q0)*rcp(q0*q1); f32x2 only for
//           lane-parallel mul/add (v_pk-formable); scalar accumulators.
//           Plain fire-and-forget atomicAdd into P[b][c] (NO counters/fences
//           -- R11's acq-rel single-line counter protocol cost ~210 us).
// grid (8,16,8) = 1024 blocks x 512 thr.
// ---------------------------------------------------------------------------
__device__ __forceinline__ float sigmoid_fast(float z) {
    float e = __builtin_amdgcn_exp2f(-1.4426950408889634f * z);
    return __builtin_amdgcn_rcpf(e + 1.0f);
}

__global__ __launch_bounds__(512, 4)
void cp_scores_kernel(const _Float16* __restrict__ pt, const _Float16* __restrict__ pc,
                      const float* __restrict__ xd, const float* __restrict__ xt,
                      float* __restrict__ P, float* __restrict__ sums_part)
{
    const int bx = blockIdx.x, by = blockIdx.y, b = blockIdx.z;
    const int i0 = bx << 5, j0 = by << 4;
    const int tid = threadIdx.x;
    const int lane = tid & 63, wv = tid >> 6;
    const int l15 = lane & 15, quad = lane >> 4;

    __shared__ _Float16 Ah[2][32][40];   // pt rows (i)
    __shared__ _Float16 Bh[2][16][40];   // pc rows (j)
    __shared__ float ws_[16][36];        // [j][i]
    __shared__ float wred[2];

    // ---- phase 1: 32x16 dot tile, MFMA, dbuf; staging threads 0..191 ----
    const int srow = tid >> 2;            // 0..47 for tid<192
    const int sch  = (tid & 3) << 3;      // 0,8,16,24
    const _Float16* Sg = ((srow < 32) ? pt + (size_t)(b * L_ + i0 + srow) * C_
                                      : pc + (size_t)(b * L_ + j0 + (srow - 32)) * C_) + sch;

    half8 v = {};
    if (tid < 192) {
        v = *(const half8*)Sg;
        if (srow < 32) *(half8*)&Ah[0][srow][sch] = v;
        else           *(half8*)&Bh[0][srow - 32][sch] = v;
    }

    f32x4 dacc = {};
    for (int ks = 0; ks < 16; ++ks) {
        const int cur = ks & 1;
        if (ks < 15 && tid < 192) { Sg += 32; v = *(const half8*)Sg; }
        __syncthreads();
        if (wv < 2) {   // waves 0-1 own the 2 16x16 quadrants (m-block = wv)
            half8 af = *(const half8*)&Ah[cur][(wv << 4) + l15][quad << 3];
            half8 bf = *(const half8*)&Bh[cur][l15][quad << 3];
            dacc = __builtin_amdgcn_mfma_f32_16x16x32_f16(af, bf, dacc, 0, 0, 0);
        }
        if (ks < 15 && tid < 192) {
            if (srow < 32) *(half8*)&Ah[cur ^ 1][srow][sch] = v;
            else           *(half8*)&Bh[cur ^ 1][srow - 32][sch] = v;
        }
    }

    float lsum = 0.f;
    if (wv < 2) {
        // C/D: col(l15) = j, row(quad*4+r) = i within 16-block (i base = wv*16)
        float4 sg;
        sg.x = sigmoid_fast(dacc[0]);
        sg.y = sigmoid_fast(dacc[1]);
        sg.z = sigmoid_fast(dacc[2]);
        sg.w = sigmoid_fast(dacc[3]);
        *(float4*)&ws_[l15][(wv << 4) + (quad << 2)] = sg;
        lsum = (sg.x + sg.y) + (sg.z + sg.w);
    }
    #pragma unroll
    for (int off = 32; off; off >>= 1) lsum += __shfl_xor(lsum, off);
    if (wv < 2 && lane == 0) wred[wv] = lsum;
    __syncthreads();                                    // ws_ + wred ready
    if (tid == 0)
        sums_part[(b << 7) | (bx << 4) | by] = wred[0] + wred[1];

    // ---- phase 2: thread = channel; dot form, scalar accumulators ----
    const int c = tid;
    const float* __restrict__ xdb = xd + (size_t)(b * L_ + i0) * C_ + c;
    const float* __restrict__ xtb = xt + (size_t)(b * L_ + j0) * C_ + c;

    float total = 0.f;
    #pragma unroll
    for (int ih = 0; ih < 2; ++ih) {
        f32x2 xds2[8];                      // 16 live VGPRs
        #pragma unroll
        for (int i = 0; i < 8; ++i) {
            xds2[i][0] = xdb[(size_t)((ih << 4) + 2 * i) * C_]     * 2.8853900817779268f;
            xds2[i][1] = xdb[(size_t)((ih << 4) + 2 * i + 1) * C_] * 2.8853900817779268f;
        }
        float A0 = 0.f, A1 = 0.f, A2 = 0.f, A3 = 0.f;
        #pragma unroll 2
        for (int jj = 0; jj < 16; ++jj) {
            const float xv = xtb[(size_t)jj * C_];
            const f32x2 xvv = {xv, xv};
            #pragma unroll
            for (int g = 0; g < 4; ++g) {
                const float4 w4 = *(const float4*)&ws_[jj][(ih << 4) + (g << 2)];
                f32x2 x0 = xds2[(g << 1)]     * xvv;    // v_pk_mul_f32
                f32x2 x1 = xds2[(g << 1) + 1] * xvv;
                f32x2 e0 = { __builtin_amdgcn_exp2f(x0[0]), __builtin_amdgcn_exp2f(x0[1]) };
                f32x2 e1 = { __builtin_amdgcn_exp2f(x1[0]), __builtin_amdgcn_exp2f(x1[1]) };
                f32x2 q0 = e0 + 1.0f;                   // v_pk_add_f32
                f32x2 q1 = e1 + 1.0f;
                const float rp0 = __builtin_amdgcn_rcpf(q0[0] * q0[1]);
                const float rp1 = __builtin_amdgcn_rcpf(q1[0] * q1[1]);
                float t0 = w4.x * q0[1];
                t0 = fmaf(w4.y, q0[0], t0);
                float t1 = w4.z * q1[1];
                t1 = fmaf(w4.w, q1[0], t1);
                if (g & 1) { A2 = fmaf(t0, rp0, A2); A3 = fmaf(t1, rp1, A3); }
                else       { A0 = fmaf(t0, rp0, A0); A1 = fmaf(t1, rp1, A1); }
            }
        }
        total += ((A0 + A1) + (A2 + A3));
    }
    atomicAdd(&P[(b << 9) | c], total);
}

// ---------------------------------------------------------------------------
// Kernel 3 (slim): S_b = sum(sums_part); cp[c] = 1 - 2*P[b][c]/S_b;
//   out[b][o] = sum_c cp[c]*Wf[c][o] + bf[o].  grid (8,8), 256 thr.
// ---------------------------------------------------------------------------
__global__ __launch_bounds__(256)
void finalize_kernel(const float* __restrict__ P, const float* __restrict__ sums_part,
                     const float* __restrict__ Wf, const float* __restrict__ bfv,
                     float* __restrict__ out)
{
    const int b = blockIdx.y;
    const int t = threadIdx.x;
    __shared__ float cp[C_];
    __shared__ float red[256];
    __shared__ float sumsh;

    red[t] = (t < 128) ? sums_part[(b << 7) | t] : 0.f;
    __syncthreads();
    for (int st = 64; st > 0; st >>= 1) {
        if (t < st) red[t] += red[t + st] + ((st == 64) ? red[t + 128] : 0.f);
        __syncthreads();
    }
    if (t == 0) sumsh = red[0];
    __syncthreads();

    const float inv = 2.0f / sumsh;
    cp[t]       = 1.0f - P[(b << 9) | t] * inv;
    cp[t + 256] = 1.0f - P[(b << 9) | (t + 256)] * inv;
    __syncthreads();

    const int o     = ((int)blockIdx.x << 6) | (t & 63);
    const int cbase = (t >> 6) << 7;   // 0,128,256,384
    float acc = 0.f;
    #pragma unroll 8
    for (int i = 0; i < 128; ++i) {
        const int cc = cbase + i;
        acc = fmaf(cp[cc], Wf[(size_t)cc * OUT_ + o], acc);
    }
    red[t] = acc;
    __syncthreads();
    if (t < 64) {
        float a = ((red[t] + red[t + 64]) + (red[t + 128] + red[t + 192]));
        out[(size_t)b * OUT_ + o] = a + bfv[o];
    }
}

// ---------------------------------------------------------------------------
extern "C" void kernel_launch(void* const* d_in, const int* in_sizes, int n_in,
                              void* d_out, int out_size, void* d_ws, size_t ws_size,
                              hipStream_t stream)
{
    const float* xd = (const float*)d_in[0];
    const float* xt = (const float*)d_in[1];
    const float* Wc = (const float*)d_in[2];
    const float* bc = (const float*)d_in[3];
    const float* Wp = (const float*)d_in[4];
    const float* bp = (const float*)d_in[5];
    const float* Wf = (const float*)d_in[6];
    const float* bf = (const float*)d_in[7];
    float* out = (float*)d_out;

    // workspace (~4 MB)
    _Float16* pt  = (_Float16*)d_ws;                 // 2 MB
    _Float16* pc  = pt + 1048576;                    // 2 MB
    float* P         = (float*)(pc + 1048576);       // 8*512 fl
    float* sums_part = P + B_ * C_;                  // 1024 fl

    proj_mfma_kernel<<<dim3(8, 32, 2), 256, 0, stream>>>(xt, Wp, bp, xd, Wc, bc, pt, pc, P);
    cp_scores_kernel<<<dim3(8, 16, 8), 512, 0, stream>>>(pt, pc, xd, xt, P, sums_part);
    finalize_kernel<<<dim3(8, 8), 256, 0, stream>>>(P, sums_part, Wf, bf, out);
}